// Round 3
// baseline (1884.082 us; speedup 1.0000x reference)
//
#include <hip/hip_runtime.h>
#include <hip/hip_bf16.h>

#define N_NODES 100000
#define N_FEAT  512
#define N_HID   256
#define N_EDGES 3200000

// CSR build: 4-way sub-bucket replication to cut atomic contention
#define KREP 4
#define NB2  (N_NODES * KREP)          // 400000 buckets

typedef __attribute__((ext_vector_type(8))) short bf16x8;
typedef __attribute__((ext_vector_type(4))) float f32x4;

__device__ __forceinline__ unsigned short bfu(float f)
{
    __hip_bfloat16 b = __float2bfloat16(f);
    return *(unsigned short*)&b;
}

__device__ __forceinline__ void llds16(const void* g, void* l)
{
    __builtin_amdgcn_global_load_lds(
        (const __attribute__((address_space(1))) unsigned int*)g,
        (__attribute__((address_space(3))) unsigned int*)l,
        16, 0, 0);
}

// ---------------- fp32 -> bf16 convert (for W) -----------------------------
__global__ __launch_bounds__(256) void convert_bf16_kernel(
    const float* __restrict__ in, unsigned short* __restrict__ outp, int n8)
{
    const int i = blockIdx.x * 256 + threadIdx.x;
    if (i >= n8) return;
    const float4 v0 = *(const float4*)(in + (size_t)i * 8);
    const float4 v1 = *(const float4*)(in + (size_t)i * 8 + 4);
    union { unsigned short s[8]; uint4 u; } pk;
    pk.s[0] = bfu(v0.x); pk.s[1] = bfu(v0.y); pk.s[2] = bfu(v0.z); pk.s[3] = bfu(v0.w);
    pk.s[4] = bfu(v1.x); pk.s[5] = bfu(v1.y); pk.s[6] = bfu(v1.z); pk.s[7] = bfu(v1.w);
    *(uint4*)(outp + (size_t)i * 8) = pk.u;
}

// ---------------- MFMA GEMM: h[n,j] = sum_k X[n,k]*W[j,k] + b[j] -----------
// BM=64 nodes, BN=256 (full H, X read once), BK=32. 4 waves, each 64x64.
#define BM 64
#define BN 256
#define BK 32

__global__ __launch_bounds__(256) void gemm_mfma(
    const float* __restrict__ X, const unsigned short* __restrict__ Wb,
    const float* __restrict__ bias, unsigned short* __restrict__ Hout, int N)
{
    __shared__ unsigned short As[BM * BK];   // [64][32] bf16, row-major
    __shared__ unsigned short Bs[BN * BK];   // [256][32] bf16, row-major

    const int tid  = threadIdx.x;
    const int wave = tid >> 6;
    const int lane = tid & 63;
    const int m0   = blockIdx.x * BM;

    // A staging: thread t -> row t>>2, k-chunk (t&3)*8 (8 fp32 -> 8 bf16)
    int arow = m0 + (tid >> 2);
    if (arow >= N) arow = N - 1;
    const float* ag = X + (size_t)arow * N_FEAT + (tid & 3) * 8;
    unsigned short* a_dst = As + tid * 8;   // byte offset tid*16 == row*64 + kp*16

    // B staging via global_load_lds: chunk c = i*256+tid -> j=c>>2, kp=c&3
    const unsigned short* bg = Wb + (size_t)(tid >> 2) * N_FEAT + (tid & 3) * 8;

    // fragment read pointers
    const unsigned short* ap = As + (lane & 15) * BK + (lane >> 4) * 8;
    const unsigned short* bp = Bs + ((size_t)(wave * 64 + (lane & 15))) * BK + (lane >> 4) * 8;

    f32x4 acc[4][4] = {};

    for (int k0 = 0; k0 < N_FEAT; k0 += BK) {
        if (k0) __syncthreads();   // previous compute done, safe to overwrite
        #pragma unroll
        for (int i = 0; i < 4; i++)
            llds16(bg + (size_t)i * 64 * N_FEAT + k0, Bs + ((size_t)(i * 256 + tid)) * 8);
        const float4 x0 = *(const float4*)(ag + k0);
        const float4 x1 = *(const float4*)(ag + k0 + 4);
        union { unsigned short s[8]; uint4 u; } pk;
        pk.s[0] = bfu(x0.x); pk.s[1] = bfu(x0.y); pk.s[2] = bfu(x0.z); pk.s[3] = bfu(x0.w);
        pk.s[4] = bfu(x1.x); pk.s[5] = bfu(x1.y); pk.s[6] = bfu(x1.z); pk.s[7] = bfu(x1.w);
        *(uint4*)a_dst = pk.u;
        __syncthreads();           // staging (incl. global_load_lds) visible

        bf16x8 af[4], bfr[4];
        #pragma unroll
        for (int mt = 0; mt < 4; mt++) af[mt] = *(const bf16x8*)(ap + mt * 16 * BK);
        #pragma unroll
        for (int nt = 0; nt < 4; nt++) bfr[nt] = *(const bf16x8*)(bp + nt * 16 * BK);
        #pragma unroll
        for (int mt = 0; mt < 4; mt++)
            #pragma unroll
            for (int nt = 0; nt < 4; nt++)
                acc[mt][nt] = __builtin_amdgcn_mfma_f32_16x16x32_bf16(
                    af[mt], bfr[nt], acc[mt][nt], 0, 0, 0);
    }

    // epilogue: C/D layout col=lane&15, row=(lane>>4)*4+reg
    const int q  = lane >> 4;
    const int c0 = lane & 15;
    float bcol[4];
    #pragma unroll
    for (int nt = 0; nt < 4; nt++) bcol[nt] = bias[wave * 64 + nt * 16 + c0];
    #pragma unroll
    for (int mt = 0; mt < 4; mt++) {
        #pragma unroll
        for (int r = 0; r < 4; r++) {
            const int row = m0 + mt * 16 + q * 4 + r;
            if (row >= N) continue;
            #pragma unroll
            for (int nt = 0; nt < 4; nt++) {
                const int col = wave * 64 + nt * 16 + c0;
                Hout[(size_t)row * N_HID + col] = bfu(acc[mt][nt][r] + bcol[nt]);
            }
        }
    }
}

// ---------------- CSR build ------------------------------------------------
// Pass 1: ONE returning atomic per edge computes counts AND per-edge rank.
// bucket = row*4 + (e&3): 4-way replication -> 4x less same-address contention.
__global__ __launch_bounds__(256) void rank_pass(
    const int* __restrict__ rows, int* __restrict__ counts2,
    int* __restrict__ rank, int E)
{
    const int e = blockIdx.x * 256 + threadIdx.x;
    if (e >= E) return;
    const int b = rows[e] * KREP + (e & (KREP - 1));
    rank[e] = atomicAdd(&counts2[b], 1);
}

// Harness-proven single-block scan (from prior passing rounds), n = NB2.
#define SCAN_T 1024
__global__ __launch_bounds__(SCAN_T) void scan_kernel(
    const int* __restrict__ counts, int* __restrict__ offsets, int n)
{
    const int tid = threadIdx.x;
    const int seg = (n + SCAN_T - 1) / SCAN_T;
    const int s0 = tid * seg;
    const int s1 = min(s0 + seg, n);

    int sum = 0;
    for (int i = s0; i < s1; i++) sum += counts[i];

    __shared__ int wsum[SCAN_T / 64];
    const int lane = tid & 63;
    const int wid  = tid >> 6;
    int v = sum;
    #pragma unroll
    for (int off = 1; off < 64; off <<= 1) {
        int t = __shfl_up(v, off);
        if (lane >= off) v += t;
    }
    if (lane == 63) wsum[wid] = v;
    __syncthreads();
    if (wid == 0 && lane < SCAN_T / 64) {
        int w = wsum[lane];
        #pragma unroll
        for (int off = 1; off < SCAN_T / 64; off <<= 1) {
            int t = __shfl_up(w, off);
            if (lane >= off) w += t;
        }
        wsum[lane] = w;
    }
    __syncthreads();
    int base = v - sum + (wid > 0 ? wsum[wid - 1] : 0);

    int run = base;
    for (int i = s0; i < s1; i++) {
        const int c = counts[i];
        offsets[i] = run;
        run += c;
    }
    if (tid == SCAN_T - 1) offsets[n] = run;
}

// Pass 2: atomic-free scatter. pos = offs2[bucket] + rank[e].
__global__ __launch_bounds__(256) void scatter_edges(
    const int* __restrict__ rows, const int* __restrict__ cols,
    const float* __restrict__ ev, const int* __restrict__ rank,
    const int* __restrict__ offs2, int2* __restrict__ ecv, int E)
{
    const int e = blockIdx.x * 256 + threadIdx.x;
    if (e >= E) return;
    const int b = rows[e] * KREP + (e & (KREP - 1));
    const int pos = offs2[b] + rank[e];
    int2 p;
    p.x = cols[e];
    p.y = __float_as_int(ev[e]);
    ecv[pos] = p;
}

// ---------------- per-row aggregation --------------------------------------
__device__ __forceinline__ void bf4_unpack(uint2 raw, float& f0, float& f1,
                                           float& f2, float& f3)
{
    f0 = __uint_as_float(raw.x << 16);
    f1 = __uint_as_float(raw.x & 0xffff0000u);
    f2 = __uint_as_float(raw.y << 16);
    f3 = __uint_as_float(raw.y & 0xffff0000u);
}

__device__ __forceinline__ uint2 bf4_pack(float f0, float f1, float f2, float f3)
{
    union { unsigned short u[4]; uint2 v; } pk;
    pk.u[0] = bfu(f0); pk.u[1] = bfu(f1); pk.u[2] = bfu(f2); pk.u[3] = bfu(f3);
    return pk.v;
}

// GCN1: aggregate -> PReLU -> store h_post bf16
__global__ __launch_bounds__(256) void agg_rows_1(
    const __hip_bfloat16* __restrict__ H, const int* __restrict__ offs2,
    const int2* __restrict__ ecv, const float* __restrict__ pa,
    __hip_bfloat16* __restrict__ hpost, int N)
{
    const int row = blockIdx.x * 4 + (threadIdx.x >> 6);
    if (row >= N) return;
    const int lane = threadIdx.x & 63;
    const int beg = offs2[row * KREP], end = offs2[row * KREP + KREP];
    const unsigned short* Hs = (const unsigned short*)H;

    float a0 = 0.f, a1 = 0.f, a2 = 0.f, a3 = 0.f;
    int e = beg;
    for (; e + 3 < end; e += 4) {
        const int2 p0 = ecv[e], p1 = ecv[e + 1], p2 = ecv[e + 2], p3 = ecv[e + 3];
        const uint2 r0 = *(const uint2*)(Hs + (size_t)p0.x * N_HID + lane * 4);
        const uint2 r1 = *(const uint2*)(Hs + (size_t)p1.x * N_HID + lane * 4);
        const uint2 r2 = *(const uint2*)(Hs + (size_t)p2.x * N_HID + lane * 4);
        const uint2 r3 = *(const uint2*)(Hs + (size_t)p3.x * N_HID + lane * 4);
        const float v0 = __int_as_float(p0.y), v1 = __int_as_float(p1.y);
        const float v2 = __int_as_float(p2.y), v3 = __int_as_float(p3.y);
        float f0, f1, f2, f3;
        bf4_unpack(r0, f0, f1, f2, f3);
        a0 += v0 * f0; a1 += v0 * f1; a2 += v0 * f2; a3 += v0 * f3;
        bf4_unpack(r1, f0, f1, f2, f3);
        a0 += v1 * f0; a1 += v1 * f1; a2 += v1 * f2; a3 += v1 * f3;
        bf4_unpack(r2, f0, f1, f2, f3);
        a0 += v2 * f0; a1 += v2 * f1; a2 += v2 * f2; a3 += v2 * f3;
        bf4_unpack(r3, f0, f1, f2, f3);
        a0 += v3 * f0; a1 += v3 * f1; a2 += v3 * f2; a3 += v3 * f3;
    }
    for (; e < end; e++) {
        const int2 p0 = ecv[e];
        const float v0 = __int_as_float(p0.y);
        const uint2 r0 = *(const uint2*)(Hs + (size_t)p0.x * N_HID + lane * 4);
        float f0, f1, f2, f3;
        bf4_unpack(r0, f0, f1, f2, f3);
        a0 += v0 * f0; a1 += v0 * f1; a2 += v0 * f2; a3 += v0 * f3;
    }
    const float al = pa[0];
    a0 = (a0 >= 0.f) ? a0 : al * a0;
    a1 = (a1 >= 0.f) ? a1 : al * a1;
    a2 = (a2 >= 0.f) ? a2 : al * a2;
    a3 = (a3 >= 0.f) ? a3 : al * a3;
    *(uint2*)((unsigned short*)hpost + (size_t)row * N_HID + lane * 4) =
        bf4_pack(a0, a1, a2, a3);
}

// GCN2: aggregate -> PReLU -> dot(v) -> score
__global__ __launch_bounds__(256) void agg_rows_2(
    const __hip_bfloat16* __restrict__ H, const int* __restrict__ offs2,
    const int2* __restrict__ ecv, const float* __restrict__ pa,
    const float* __restrict__ vbuf, const float* __restrict__ bilb,
    float* __restrict__ out, int N)
{
    __shared__ float vs[N_HID];
    vs[threadIdx.x] = vbuf[threadIdx.x];
    __syncthreads();

    const int row = blockIdx.x * 4 + (threadIdx.x >> 6);
    if (row >= N) return;
    const int lane = threadIdx.x & 63;
    const int beg = offs2[row * KREP], end = offs2[row * KREP + KREP];
    const unsigned short* Hs = (const unsigned short*)H;

    float a0 = 0.f, a1 = 0.f, a2 = 0.f, a3 = 0.f;
    int e = beg;
    for (; e + 3 < end; e += 4) {
        const int2 p0 = ecv[e], p1 = ecv[e + 1], p2 = ecv[e + 2], p3 = ecv[e + 3];
        const uint2 r0 = *(const uint2*)(Hs + (size_t)p0.x * N_HID + lane * 4);
        const uint2 r1 = *(const uint2*)(Hs + (size_t)p1.x * N_HID + lane * 4);
        const uint2 r2 = *(const uint2*)(Hs + (size_t)p2.x * N_HID + lane * 4);
        const uint2 r3 = *(const uint2*)(Hs + (size_t)p3.x * N_HID + lane * 4);
        const float v0 = __int_as_float(p0.y), v1 = __int_as_float(p1.y);
        const float v2 = __int_as_float(p2.y), v3 = __int_as_float(p3.y);
        float f0, f1, f2, f3;
        bf4_unpack(r0, f0, f1, f2, f3);
        a0 += v0 * f0; a1 += v0 * f1; a2 += v0 * f2; a3 += v0 * f3;
        bf4_unpack(r1, f0, f1, f2, f3);
        a0 += v1 * f0; a1 += v1 * f1; a2 += v1 * f2; a3 += v1 * f3;
        bf4_unpack(r2, f0, f1, f2, f3);
        a0 += v2 * f0; a1 += v2 * f1; a2 += v2 * f2; a3 += v2 * f3;
        bf4_unpack(r3, f0, f1, f2, f3);
        a0 += v3 * f0; a1 += v3 * f1; a2 += v3 * f2; a3 += v3 * f3;
    }
    for (; e < end; e++) {
        const int2 p0 = ecv[e];
        const float v0 = __int_as_float(p0.y);
        const uint2 r0 = *(const uint2*)(Hs + (size_t)p0.x * N_HID + lane * 4);
        float f0, f1, f2, f3;
        bf4_unpack(r0, f0, f1, f2, f3);
        a0 += v0 * f0; a1 += v0 * f1; a2 += v0 * f2; a3 += v0 * f3;
    }
    const float al = pa[0];
    a0 = (a0 >= 0.f) ? a0 : al * a0;
    a1 = (a1 >= 0.f) ? a1 : al * a1;
    a2 = (a2 >= 0.f) ? a2 : al * a2;
    a3 = (a3 >= 0.f) ? a3 : al * a3;

    float p = a0 * vs[lane * 4 + 0] + a1 * vs[lane * 4 + 1] +
              a2 * vs[lane * 4 + 2] + a3 * vs[lane * 4 + 3];
    #pragma unroll
    for (int off = 32; off > 0; off >>= 1) p += __shfl_down(p, off);
    if (lane == 0) out[row] = p + bilb[0];
}

// ---------------- column sums of bf16 h_post -------------------------------
#define NPB 256
__global__ __launch_bounds__(256) void colsum_kernel(
    const __hip_bfloat16* __restrict__ hpost, float* __restrict__ colsum, int N)
{
    const int j = threadIdx.x;
    const int n0 = blockIdx.x * NPB;
    const int n1 = min(n0 + NPB, N);
    float s = 0.f;
    for (int n = n0; n < n1; n++)
        s += __bfloat162float(hpost[(size_t)n * N_HID + j]);
    atomicAdd(&colsum[j], s);
}

// ---------------- v = bil_w @ sigmoid(colsum/N) ----------------------------
__global__ __launch_bounds__(256) void compute_v(
    const float* __restrict__ colsum, const float* __restrict__ bilw,
    float* __restrict__ vbuf, int N)
{
    __shared__ float s[N_HID];
    const int t = threadIdx.x;
    const float mean = colsum[t] / (float)N;
    s[t] = 1.f / (1.f + expf(-mean));
    __syncthreads();
    float acc = 0.f;
    #pragma unroll 4
    for (int g = 0; g < N_HID; g++) acc += bilw[t * N_HID + g] * s[g];
    vbuf[t] = acc;
}

// ---------------- score_1: dot(h_post bf16, v) -----------------------------
__global__ __launch_bounds__(256) void score_kernel(
    const __hip_bfloat16* __restrict__ hpost, const float* __restrict__ vbuf,
    const float* __restrict__ bilb, float* __restrict__ out, int N)
{
    __shared__ float vs[N_HID];
    vs[threadIdx.x] = vbuf[threadIdx.x];
    __syncthreads();
    const int n = blockIdx.x * 4 + (threadIdx.x >> 6);
    if (n >= N) return;
    const int lane = threadIdx.x & 63;
    const uint2 raw = *(const uint2*)((const unsigned short*)hpost +
                                      (size_t)n * N_HID + lane * 4);
    float f0, f1, f2, f3;
    bf4_unpack(raw, f0, f1, f2, f3);
    float p = f0 * vs[lane * 4 + 0] + f1 * vs[lane * 4 + 1] +
              f2 * vs[lane * 4 + 2] + f3 * vs[lane * 4 + 3];
    #pragma unroll
    for (int off = 32; off > 0; off >>= 1) p += __shfl_down(p, off);
    if (lane == 0) out[n] = p + bilb[0];
}

extern "C" void kernel_launch(void* const* d_in, const int* in_sizes, int n_in,
                              void* d_out, int out_size, void* d_ws, size_t ws_size,
                              hipStream_t stream)
{
    const float* x1     = (const float*)d_in[0];
    const float* x2     = (const float*)d_in[1];
    const float* evals  = (const float*)d_in[2];
    const float* fc_w   = (const float*)d_in[3];
    const float* fc_b   = (const float*)d_in[4];
    const float* prelua = (const float*)d_in[5];
    const float* bil_w  = (const float*)d_in[6];
    const float* bil_b  = (const float*)d_in[7];
    const int*   eidx   = (const int*)d_in[8];
    const int*   erow   = eidx;
    const int*   ecol   = eidx + N_EDGES;
    float* out = (float*)d_out;

    // workspace layout (bytes) — persistent:
    char* ws = (char*)d_ws;
    __hip_bfloat16* h_bf   = (__hip_bfloat16*)(ws);                         // 51.2 MB
    __hip_bfloat16* hpost1 = (__hip_bfloat16*)(ws + (size_t)52 * 1000000);  // 51.2 MB
    int2*  ecv    = (int2*) (ws + (size_t)104 * 1000000);                   // 25.6 MB
    unsigned short* wbf = (unsigned short*)(ws + (size_t)130 * 1000000);    // 262 KB
    int*   offs2  = (int*)  (ws + (size_t)130400000);                       // 1.6 MB (NB2+1)
    float* colsum = (float*)(ws + (size_t)132100000);                       // 1 KB
    float* vbuf   = colsum + N_HID;
    // transients (inside h_bf region; all dead before gemm_mfma writes h_bf):
    int*   counts2 = (int*)(ws);                                            // 1.6 MB
    int*   rank    = (int*)(ws + (size_t)4000000);                          // 12.8 MB

    const int gemm_blocks = (N_NODES + BM - 1) / BM;
    const int eblocks   = (N_EDGES + 255) / 256;
    const int rowblocks = (N_NODES + 3) / 4;
    const int csblocks  = (N_NODES + NPB - 1) / NPB;

    // ---- CSR build (single atomic pass) + W convert ----
    hipMemsetAsync(counts2, 0, NB2 * sizeof(int), stream);
    hipMemsetAsync(colsum, 0, N_HID * sizeof(float), stream);
    rank_pass<<<eblocks, 256, 0, stream>>>(erow, counts2, rank, N_EDGES);
    scan_kernel<<<1, SCAN_T, 0, stream>>>(counts2, offs2, NB2);
    scatter_edges<<<eblocks, 256, 0, stream>>>(erow, ecol, evals, rank,
                                               offs2, ecv, N_EDGES);
    convert_bf16_kernel<<<(N_HID * N_FEAT / 8 + 255) / 256, 256, 0, stream>>>(
        fc_w, wbf, N_HID * N_FEAT / 8);

    // ---- GCN 1 ----
    gemm_mfma<<<gemm_blocks, 256, 0, stream>>>(x1, wbf, fc_b,
                                               (unsigned short*)h_bf, N_NODES);
    agg_rows_1<<<rowblocks, 256, 0, stream>>>(h_bf, offs2, ecv, prelua,
                                              hpost1, N_NODES);
    colsum_kernel<<<csblocks, 256, 0, stream>>>(hpost1, colsum, N_NODES);
    compute_v<<<1, 256, 0, stream>>>(colsum, bil_w, vbuf, N_NODES);
    score_kernel<<<rowblocks, 256, 0, stream>>>(hpost1, vbuf, bil_b, out, N_NODES);

    // ---- GCN 2 (reuses h_bf, CSR; fused score) ----
    gemm_mfma<<<gemm_blocks, 256, 0, stream>>>(x2, wbf, fc_b,
                                               (unsigned short*)h_bf, N_NODES);
    agg_rows_2<<<rowblocks, 256, 0, stream>>>(h_bf, offs2, ecv, prelua,
                                              vbuf, bil_b, out + N_NODES, N_NODES);
}

// Round 4
// 1252.727 us; speedup vs baseline: 1.5040x; 1.5040x over previous
//
#include <hip/hip_runtime.h>
#include <hip/hip_bf16.h>

#define N_NODES 100000
#define N_FEAT  512
#define N_HID   256
#define N_EDGES 3200000

// CSR build: 4-way sub-bucket replication to cut atomic contention
#define KREP 4
#define NB2  (N_NODES * KREP)          // 400000 buckets
#define SCC  1024                      // elements per scan block
#define SCG  ((NB2 + SCC - 1) / SCC)   // 391 scan blocks (<= 512)

typedef __attribute__((ext_vector_type(8))) short bf16x8;
typedef __attribute__((ext_vector_type(4))) float f32x4;

__device__ __forceinline__ unsigned short bfu(float f)
{
    __hip_bfloat16 b = __float2bfloat16(f);
    return *(unsigned short*)&b;
}

__device__ __forceinline__ void llds16(const void* g, void* l)
{
    __builtin_amdgcn_global_load_lds(
        (const __attribute__((address_space(1))) unsigned int*)g,
        (__attribute__((address_space(3))) unsigned int*)l,
        16, 0, 0);
}

// ---------------- fp32 -> bf16 convert (for W) -----------------------------
__global__ __launch_bounds__(256) void convert_bf16_kernel(
    const float* __restrict__ in, unsigned short* __restrict__ outp, int n8)
{
    const int i = blockIdx.x * 256 + threadIdx.x;
    if (i >= n8) return;
    const float4 v0 = *(const float4*)(in + (size_t)i * 8);
    const float4 v1 = *(const float4*)(in + (size_t)i * 8 + 4);
    union { unsigned short s[8]; uint4 u; } pk;
    pk.s[0] = bfu(v0.x); pk.s[1] = bfu(v0.y); pk.s[2] = bfu(v0.z); pk.s[3] = bfu(v0.w);
    pk.s[4] = bfu(v1.x); pk.s[5] = bfu(v1.y); pk.s[6] = bfu(v1.z); pk.s[7] = bfu(v1.w);
    *(uint4*)(outp + (size_t)i * 8) = pk.u;
}

// ---------------- MFMA GEMM: h[n,j] = sum_k X[n,k]*W[j,k] + b[j] -----------
// BM=64 nodes, BN=256 (full H, X read once), BK=32. 4 waves, each 64x64.
#define BM 64
#define BN 256
#define BK 32

__global__ __launch_bounds__(256) void gemm_mfma(
    const float* __restrict__ X, const unsigned short* __restrict__ Wb,
    const float* __restrict__ bias, unsigned short* __restrict__ Hout, int N)
{
    __shared__ unsigned short As[BM * BK];   // [64][32] bf16, row-major
    __shared__ unsigned short Bs[BN * BK];   // [256][32] bf16, row-major

    const int tid  = threadIdx.x;
    const int wave = tid >> 6;
    const int lane = tid & 63;
    const int m0   = blockIdx.x * BM;

    // A staging: thread t -> row t>>2, k-chunk (t&3)*8 (8 fp32 -> 8 bf16)
    int arow = m0 + (tid >> 2);
    if (arow >= N) arow = N - 1;
    const float* ag = X + (size_t)arow * N_FEAT + (tid & 3) * 8;
    unsigned short* a_dst = As + tid * 8;   // byte offset tid*16 == row*64 + kp*16

    // B staging via global_load_lds: chunk c = i*256+tid -> j=c>>2, kp=c&3
    const unsigned short* bg = Wb + (size_t)(tid >> 2) * N_FEAT + (tid & 3) * 8;

    // fragment read pointers
    const unsigned short* ap = As + (lane & 15) * BK + (lane >> 4) * 8;
    const unsigned short* bp = Bs + ((size_t)(wave * 64 + (lane & 15))) * BK + (lane >> 4) * 8;

    f32x4 acc[4][4] = {};

    for (int k0 = 0; k0 < N_FEAT; k0 += BK) {
        if (k0) __syncthreads();   // previous compute done, safe to overwrite
        #pragma unroll
        for (int i = 0; i < 4; i++)
            llds16(bg + (size_t)i * 64 * N_FEAT + k0, Bs + ((size_t)(i * 256 + tid)) * 8);
        const float4 x0 = *(const float4*)(ag + k0);
        const float4 x1 = *(const float4*)(ag + k0 + 4);
        union { unsigned short s[8]; uint4 u; } pk;
        pk.s[0] = bfu(x0.x); pk.s[1] = bfu(x0.y); pk.s[2] = bfu(x0.z); pk.s[3] = bfu(x0.w);
        pk.s[4] = bfu(x1.x); pk.s[5] = bfu(x1.y); pk.s[6] = bfu(x1.z); pk.s[7] = bfu(x1.w);
        *(uint4*)a_dst = pk.u;
        __syncthreads();           // staging (incl. global_load_lds) visible

        bf16x8 af[4], bfr[4];
        #pragma unroll
        for (int mt = 0; mt < 4; mt++) af[mt] = *(const bf16x8*)(ap + mt * 16 * BK);
        #pragma unroll
        for (int nt = 0; nt < 4; nt++) bfr[nt] = *(const bf16x8*)(bp + nt * 16 * BK);
        #pragma unroll
        for (int mt = 0; mt < 4; mt++)
            #pragma unroll
            for (int nt = 0; nt < 4; nt++)
                acc[mt][nt] = __builtin_amdgcn_mfma_f32_16x16x32_bf16(
                    af[mt], bfr[nt], acc[mt][nt], 0, 0, 0);
    }

    // epilogue: C/D layout col=lane&15, row=(lane>>4)*4+reg
    const int q  = lane >> 4;
    const int c0 = lane & 15;
    float bcol[4];
    #pragma unroll
    for (int nt = 0; nt < 4; nt++) bcol[nt] = bias[wave * 64 + nt * 16 + c0];
    #pragma unroll
    for (int mt = 0; mt < 4; mt++) {
        #pragma unroll
        for (int r = 0; r < 4; r++) {
            const int row = m0 + mt * 16 + q * 4 + r;
            if (row >= N) continue;
            #pragma unroll
            for (int nt = 0; nt < 4; nt++) {
                const int col = wave * 64 + nt * 16 + c0;
                Hout[(size_t)row * N_HID + col] = bfu(acc[mt][nt][r] + bcol[nt]);
            }
        }
    }
}

// ---------------- CSR build ------------------------------------------------
// Pass 1: ONE returning atomic per edge computes counts AND per-edge rank.
// bucket = row*4 + (e&3): 4-way replication -> 4x less same-address contention.
__global__ __launch_bounds__(256) void rank_pass(
    const int* __restrict__ rows, int* __restrict__ counts2,
    int* __restrict__ rank, int E)
{
    const int e = blockIdx.x * 256 + threadIdx.x;
    if (e >= E) return;
    const int b = rows[e] * KREP + (e & (KREP - 1));
    rank[e] = atomicAdd(&counts2[b], 1);
}

// ---- parallel exclusive scan over NB2 bucket counts (3 dispatches) --------
// Conservative: shared-memory tree reduce / Hillis-Steele, full barriers.

// Pass A: per-block sums of SCC counts.
__global__ __launch_bounds__(256) void scan_sum(
    const int* __restrict__ counts, int* __restrict__ bsum, int n)
{
    __shared__ int sh[256];
    const int g = blockIdx.x, t = threadIdx.x;
    const int base = g * SCC;
    int s = 0;
    #pragma unroll
    for (int i = 0; i < 4; i++) {
        const int idx = base + t + i * 256;
        if (idx < n) s += counts[idx];
    }
    sh[t] = s;
    __syncthreads();
    for (int off = 128; off > 0; off >>= 1) {
        if (t < off) sh[t] += sh[t + off];
        __syncthreads();
    }
    if (t == 0) bsum[g] = sh[0];
}

// Pass B: single-block exclusive scan of the G block sums (G <= 512).
__global__ __launch_bounds__(512) void scan_base(
    const int* __restrict__ bsum, int* __restrict__ bbase, int G)
{
    __shared__ int sh[512];
    const int t = threadIdx.x;
    const int v = (t < G) ? bsum[t] : 0;
    sh[t] = v;
    __syncthreads();
    for (int off = 1; off < 512; off <<= 1) {
        const int u = (t >= off) ? sh[t - off] : 0;
        __syncthreads();
        sh[t] += u;
        __syncthreads();
    }
    if (t < G) bbase[t] = sh[t] - v;   // exclusive prefix
}

// Pass C: per-block exclusive scan of SCC counts + block base -> offs2.
__global__ __launch_bounds__(256) void scan_write(
    const int* __restrict__ counts, const int* __restrict__ bbase,
    int* __restrict__ offs2, int n, int E)
{
    __shared__ int sh[256];
    const int g = blockIdx.x, t = threadIdx.x;
    const int base = g * SCC;
    int c[4];
    int s = 0;
    #pragma unroll
    for (int i = 0; i < 4; i++) {
        const int idx = base + t * 4 + i;
        c[i] = (idx < n) ? counts[idx] : 0;
        s += c[i];
    }
    sh[t] = s;
    __syncthreads();
    for (int off = 1; off < 256; off <<= 1) {
        const int u = (t >= off) ? sh[t - off] : 0;
        __syncthreads();
        sh[t] += u;
        __syncthreads();
    }
    int run = bbase[g] + sh[t] - s;    // exclusive prefix of this thread's chunk
    #pragma unroll
    for (int i = 0; i < 4; i++) {
        const int idx = base + t * 4 + i;
        if (idx < n) offs2[idx] = run;
        run += c[i];
    }
    if (g == 0 && t == 0) offs2[n] = E;
}

// Pass 2: atomic-free scatter. pos = offs2[bucket] + rank[e].
__global__ __launch_bounds__(256) void scatter_edges(
    const int* __restrict__ rows, const int* __restrict__ cols,
    const float* __restrict__ ev, const int* __restrict__ rank,
    const int* __restrict__ offs2, int2* __restrict__ ecv, int E)
{
    const int e = blockIdx.x * 256 + threadIdx.x;
    if (e >= E) return;
    const int b = rows[e] * KREP + (e & (KREP - 1));
    const int pos = offs2[b] + rank[e];
    int2 p;
    p.x = cols[e];
    p.y = __float_as_int(ev[e]);
    ecv[pos] = p;
}

// ---------------- per-row aggregation --------------------------------------
__device__ __forceinline__ void bf4_unpack(uint2 raw, float& f0, float& f1,
                                           float& f2, float& f3)
{
    f0 = __uint_as_float(raw.x << 16);
    f1 = __uint_as_float(raw.x & 0xffff0000u);
    f2 = __uint_as_float(raw.y << 16);
    f3 = __uint_as_float(raw.y & 0xffff0000u);
}

__device__ __forceinline__ uint2 bf4_pack(float f0, float f1, float f2, float f3)
{
    union { unsigned short u[4]; uint2 v; } pk;
    pk.u[0] = bfu(f0); pk.u[1] = bfu(f1); pk.u[2] = bfu(f2); pk.u[3] = bfu(f3);
    return pk.v;
}

// GCN1: aggregate -> PReLU -> store h_post bf16
__global__ __launch_bounds__(256) void agg_rows_1(
    const __hip_bfloat16* __restrict__ H, const int* __restrict__ offs2,
    const int2* __restrict__ ecv, const float* __restrict__ pa,
    __hip_bfloat16* __restrict__ hpost, int N)
{
    const int row = blockIdx.x * 4 + (threadIdx.x >> 6);
    if (row >= N) return;
    const int lane = threadIdx.x & 63;
    const int beg = offs2[row * KREP], end = offs2[row * KREP + KREP];
    const unsigned short* Hs = (const unsigned short*)H;

    float a0 = 0.f, a1 = 0.f, a2 = 0.f, a3 = 0.f;
    int e = beg;
    for (; e + 3 < end; e += 4) {
        const int2 p0 = ecv[e], p1 = ecv[e + 1], p2 = ecv[e + 2], p3 = ecv[e + 3];
        const uint2 r0 = *(const uint2*)(Hs + (size_t)p0.x * N_HID + lane * 4);
        const uint2 r1 = *(const uint2*)(Hs + (size_t)p1.x * N_HID + lane * 4);
        const uint2 r2 = *(const uint2*)(Hs + (size_t)p2.x * N_HID + lane * 4);
        const uint2 r3 = *(const uint2*)(Hs + (size_t)p3.x * N_HID + lane * 4);
        const float v0 = __int_as_float(p0.y), v1 = __int_as_float(p1.y);
        const float v2 = __int_as_float(p2.y), v3 = __int_as_float(p3.y);
        float f0, f1, f2, f3;
        bf4_unpack(r0, f0, f1, f2, f3);
        a0 += v0 * f0; a1 += v0 * f1; a2 += v0 * f2; a3 += v0 * f3;
        bf4_unpack(r1, f0, f1, f2, f3);
        a0 += v1 * f0; a1 += v1 * f1; a2 += v1 * f2; a3 += v1 * f3;
        bf4_unpack(r2, f0, f1, f2, f3);
        a0 += v2 * f0; a1 += v2 * f1; a2 += v2 * f2; a3 += v2 * f3;
        bf4_unpack(r3, f0, f1, f2, f3);
        a0 += v3 * f0; a1 += v3 * f1; a2 += v3 * f2; a3 += v3 * f3;
    }
    for (; e < end; e++) {
        const int2 p0 = ecv[e];
        const float v0 = __int_as_float(p0.y);
        const uint2 r0 = *(const uint2*)(Hs + (size_t)p0.x * N_HID + lane * 4);
        float f0, f1, f2, f3;
        bf4_unpack(r0, f0, f1, f2, f3);
        a0 += v0 * f0; a1 += v0 * f1; a2 += v0 * f2; a3 += v0 * f3;
    }
    const float al = pa[0];
    a0 = (a0 >= 0.f) ? a0 : al * a0;
    a1 = (a1 >= 0.f) ? a1 : al * a1;
    a2 = (a2 >= 0.f) ? a2 : al * a2;
    a3 = (a3 >= 0.f) ? a3 : al * a3;
    *(uint2*)((unsigned short*)hpost + (size_t)row * N_HID + lane * 4) =
        bf4_pack(a0, a1, a2, a3);
}

// GCN2: aggregate -> PReLU -> dot(v) -> score
__global__ __launch_bounds__(256) void agg_rows_2(
    const __hip_bfloat16* __restrict__ H, const int* __restrict__ offs2,
    const int2* __restrict__ ecv, const float* __restrict__ pa,
    const float* __restrict__ vbuf, const float* __restrict__ bilb,
    float* __restrict__ out, int N)
{
    __shared__ float vs[N_HID];
    vs[threadIdx.x] = vbuf[threadIdx.x];
    __syncthreads();

    const int row = blockIdx.x * 4 + (threadIdx.x >> 6);
    if (row >= N) return;
    const int lane = threadIdx.x & 63;
    const int beg = offs2[row * KREP], end = offs2[row * KREP + KREP];
    const unsigned short* Hs = (const unsigned short*)H;

    float a0 = 0.f, a1 = 0.f, a2 = 0.f, a3 = 0.f;
    int e = beg;
    for (; e + 3 < end; e += 4) {
        const int2 p0 = ecv[e], p1 = ecv[e + 1], p2 = ecv[e + 2], p3 = ecv[e + 3];
        const uint2 r0 = *(const uint2*)(Hs + (size_t)p0.x * N_HID + lane * 4);
        const uint2 r1 = *(const uint2*)(Hs + (size_t)p1.x * N_HID + lane * 4);
        const uint2 r2 = *(const uint2*)(Hs + (size_t)p2.x * N_HID + lane * 4);
        const uint2 r3 = *(const uint2*)(Hs + (size_t)p3.x * N_HID + lane * 4);
        const float v0 = __int_as_float(p0.y), v1 = __int_as_float(p1.y);
        const float v2 = __int_as_float(p2.y), v3 = __int_as_float(p3.y);
        float f0, f1, f2, f3;
        bf4_unpack(r0, f0, f1, f2, f3);
        a0 += v0 * f0; a1 += v0 * f1; a2 += v0 * f2; a3 += v0 * f3;
        bf4_unpack(r1, f0, f1, f2, f3);
        a0 += v1 * f0; a1 += v1 * f1; a2 += v1 * f2; a3 += v1 * f3;
        bf4_unpack(r2, f0, f1, f2, f3);
        a0 += v2 * f0; a1 += v2 * f1; a2 += v2 * f2; a3 += v2 * f3;
        bf4_unpack(r3, f0, f1, f2, f3);
        a0 += v3 * f0; a1 += v3 * f1; a2 += v3 * f2; a3 += v3 * f3;
    }
    for (; e < end; e++) {
        const int2 p0 = ecv[e];
        const float v0 = __int_as_float(p0.y);
        const uint2 r0 = *(const uint2*)(Hs + (size_t)p0.x * N_HID + lane * 4);
        float f0, f1, f2, f3;
        bf4_unpack(r0, f0, f1, f2, f3);
        a0 += v0 * f0; a1 += v0 * f1; a2 += v0 * f2; a3 += v0 * f3;
    }
    const float al = pa[0];
    a0 = (a0 >= 0.f) ? a0 : al * a0;
    a1 = (a1 >= 0.f) ? a1 : al * a1;
    a2 = (a2 >= 0.f) ? a2 : al * a2;
    a3 = (a3 >= 0.f) ? a3 : al * a3;

    float p = a0 * vs[lane * 4 + 0] + a1 * vs[lane * 4 + 1] +
              a2 * vs[lane * 4 + 2] + a3 * vs[lane * 4 + 3];
    #pragma unroll
    for (int off = 32; off > 0; off >>= 1) p += __shfl_down(p, off);
    if (lane == 0) out[row] = p + bilb[0];
}

// ---------------- column sums of bf16 h_post -------------------------------
#define NPB 256
__global__ __launch_bounds__(256) void colsum_kernel(
    const __hip_bfloat16* __restrict__ hpost, float* __restrict__ colsum, int N)
{
    const int j = threadIdx.x;
    const int n0 = blockIdx.x * NPB;
    const int n1 = min(n0 + NPB, N);
    float s = 0.f;
    for (int n = n0; n < n1; n++)
        s += __bfloat162float(hpost[(size_t)n * N_HID + j]);
    atomicAdd(&colsum[j], s);
}

// ---------------- v = bil_w @ sigmoid(colsum/N) ----------------------------
__global__ __launch_bounds__(256) void compute_v(
    const float* __restrict__ colsum, const float* __restrict__ bilw,
    float* __restrict__ vbuf, int N)
{
    __shared__ float s[N_HID];
    const int t = threadIdx.x;
    const float mean = colsum[t] / (float)N;
    s[t] = 1.f / (1.f + expf(-mean));
    __syncthreads();
    float acc = 0.f;
    #pragma unroll 4
    for (int g = 0; g < N_HID; g++) acc += bilw[t * N_HID + g] * s[g];
    vbuf[t] = acc;
}

// ---------------- score_1: dot(h_post bf16, v) -----------------------------
__global__ __launch_bounds__(256) void score_kernel(
    const __hip_bfloat16* __restrict__ hpost, const float* __restrict__ vbuf,
    const float* __restrict__ bilb, float* __restrict__ out, int N)
{
    __shared__ float vs[N_HID];
    vs[threadIdx.x] = vbuf[threadIdx.x];
    __syncthreads();
    const int n = blockIdx.x * 4 + (threadIdx.x >> 6);
    if (n >= N) return;
    const int lane = threadIdx.x & 63;
    const uint2 raw = *(const uint2*)((const unsigned short*)hpost +
                                      (size_t)n * N_HID + lane * 4);
    float f0, f1, f2, f3;
    bf4_unpack(raw, f0, f1, f2, f3);
    float p = f0 * vs[lane * 4 + 0] + f1 * vs[lane * 4 + 1] +
              f2 * vs[lane * 4 + 2] + f3 * vs[lane * 4 + 3];
    #pragma unroll
    for (int off = 32; off > 0; off >>= 1) p += __shfl_down(p, off);
    if (lane == 0) out[n] = p + bilb[0];
}

extern "C" void kernel_launch(void* const* d_in, const int* in_sizes, int n_in,
                              void* d_out, int out_size, void* d_ws, size_t ws_size,
                              hipStream_t stream)
{
    const float* x1     = (const float*)d_in[0];
    const float* x2     = (const float*)d_in[1];
    const float* evals  = (const float*)d_in[2];
    const float* fc_w   = (const float*)d_in[3];
    const float* fc_b   = (const float*)d_in[4];
    const float* prelua = (const float*)d_in[5];
    const float* bil_w  = (const float*)d_in[6];
    const float* bil_b  = (const float*)d_in[7];
    const int*   eidx   = (const int*)d_in[8];
    const int*   erow   = eidx;
    const int*   ecol   = eidx + N_EDGES;
    float* out = (float*)d_out;

    // workspace layout (bytes) — persistent:
    char* ws = (char*)d_ws;
    __hip_bfloat16* h_bf   = (__hip_bfloat16*)(ws);                         // 51.2 MB
    __hip_bfloat16* hpost1 = (__hip_bfloat16*)(ws + (size_t)52 * 1000000);  // 51.2 MB
    int2*  ecv    = (int2*) (ws + (size_t)104 * 1000000);                   // 25.6 MB
    unsigned short* wbf = (unsigned short*)(ws + (size_t)130 * 1000000);    // 262 KB
    int*   offs2  = (int*)  (ws + (size_t)130400000);                       // 1.6 MB (NB2+1)
    float* colsum = (float*)(ws + (size_t)132100000);                       // 1 KB
    float* vbuf   = colsum + N_HID;
    // transients (inside h_bf region; all dead before gemm_mfma writes h_bf):
    int*   counts2 = (int*)(ws);                                            // 1.6 MB
    int*   bsum    = (int*)(ws + (size_t)2000000);                          // 1.6 KB
    int*   bbase   = (int*)(ws + (size_t)2010000);                          // 1.6 KB
    int*   rank    = (int*)(ws + (size_t)4000000);                          // 12.8 MB

    const int gemm_blocks = (N_NODES + BM - 1) / BM;
    const int eblocks   = (N_EDGES + 255) / 256;
    const int rowblocks = (N_NODES + 3) / 4;
    const int csblocks  = (N_NODES + NPB - 1) / NPB;

    // ---- CSR build (single atomic pass, parallel scan) + W convert ----
    hipMemsetAsync(counts2, 0, NB2 * sizeof(int), stream);
    hipMemsetAsync(colsum, 0, N_HID * sizeof(float), stream);
    rank_pass<<<eblocks, 256, 0, stream>>>(erow, counts2, rank, N_EDGES);
    scan_sum<<<SCG, 256, 0, stream>>>(counts2, bsum, NB2);
    scan_base<<<1, 512, 0, stream>>>(bsum, bbase, SCG);
    scan_write<<<SCG, 256, 0, stream>>>(counts2, bbase, offs2, NB2, N_EDGES);
    scatter_edges<<<eblocks, 256, 0, stream>>>(erow, ecol, evals, rank,
                                               offs2, ecv, N_EDGES);
    convert_bf16_kernel<<<(N_HID * N_FEAT / 8 + 255) / 256, 256, 0, stream>>>(
        fc_w, wbf, N_HID * N_FEAT / 8);

    // ---- GCN 1 ----
    gemm_mfma<<<gemm_blocks, 256, 0, stream>>>(x1, wbf, fc_b,
                                               (unsigned short*)h_bf, N_NODES);
    agg_rows_1<<<rowblocks, 256, 0, stream>>>(h_bf, offs2, ecv, prelua,
                                              hpost1, N_NODES);
    colsum_kernel<<<csblocks, 256, 0, stream>>>(hpost1, colsum, N_NODES);
    compute_v<<<1, 256, 0, stream>>>(colsum, bil_w, vbuf, N_NODES);
    score_kernel<<<rowblocks, 256, 0, stream>>>(hpost1, vbuf, bil_b, out, N_NODES);

    // ---- GCN 2 (reuses h_bf, CSR; fused score) ----
    gemm_mfma<<<gemm_blocks, 256, 0, stream>>>(x2, wbf, fc_b,
                                               (unsigned short*)h_bf, N_NODES);
    agg_rows_2<<<rowblocks, 256, 0, stream>>>(h_bf, offs2, ecv, prelua,
                                              vbuf, bil_b, out + N_NODES, N_NODES);
}

// Round 5
// 1249.882 us; speedup vs baseline: 1.5074x; 1.0023x over previous
//
#include <hip/hip_runtime.h>
#include <hip/hip_bf16.h>

#define N_NODES 100000
#define N_FEAT  512
#define N_HID   256
#define N_EDGES 3200000

// CSR build: 4-way sub-bucket replication to cut atomic contention
#define KREP 4
#define NB2  (N_NODES * KREP)          // 400000 buckets
#define SCC  1024                      // elements per scan block
#define SCG  ((NB2 + SCC - 1) / SCC)   // 391 scan blocks (<= 512)

typedef __attribute__((ext_vector_type(8))) short bf16x8;
typedef __attribute__((ext_vector_type(4))) float f32x4;

__device__ __forceinline__ unsigned short bfu(float f)
{
    __hip_bfloat16 b = __float2bfloat16(f);
    return *(unsigned short*)&b;
}

__device__ __forceinline__ void llds16(const void* g, void* l)
{
    __builtin_amdgcn_global_load_lds(
        (const __attribute__((address_space(1))) unsigned int*)g,
        (__attribute__((address_space(3))) unsigned int*)l,
        16, 0, 0);
}

// ---------------- fp32 -> bf16 convert (for W) -----------------------------
__global__ __launch_bounds__(256) void convert_bf16_kernel(
    const float* __restrict__ in, unsigned short* __restrict__ outp, int n8)
{
    const int i = blockIdx.x * 256 + threadIdx.x;
    if (i >= n8) return;
    const float4 v0 = *(const float4*)(in + (size_t)i * 8);
    const float4 v1 = *(const float4*)(in + (size_t)i * 8 + 4);
    union { unsigned short s[8]; uint4 u; } pk;
    pk.s[0] = bfu(v0.x); pk.s[1] = bfu(v0.y); pk.s[2] = bfu(v0.z); pk.s[3] = bfu(v0.w);
    pk.s[4] = bfu(v1.x); pk.s[5] = bfu(v1.y); pk.s[6] = bfu(v1.z); pk.s[7] = bfu(v1.w);
    *(uint4*)(outp + (size_t)i * 8) = pk.u;
}

// ---------------- MFMA GEMM: h[n,j] = sum_k X[n,k]*W[j,k] + b[j] -----------
// BM=64 nodes, BN=256 (full H, X read once), BK=32. 4 waves, each 64x64.
#define BM 64
#define BN 256
#define BK 32

__global__ __launch_bounds__(256) void gemm_mfma(
    const float* __restrict__ X, const unsigned short* __restrict__ Wb,
    const float* __restrict__ bias, unsigned short* __restrict__ Hout, int N)
{
    __shared__ unsigned short As[BM * BK];   // [64][32] bf16, row-major
    __shared__ unsigned short Bs[BN * BK];   // [256][32] bf16, row-major

    const int tid  = threadIdx.x;
    const int wave = tid >> 6;
    const int lane = tid & 63;
    const int m0   = blockIdx.x * BM;

    // A staging: thread t -> row t>>2, k-chunk (t&3)*8 (8 fp32 -> 8 bf16)
    int arow = m0 + (tid >> 2);
    if (arow >= N) arow = N - 1;
    const float* ag = X + (size_t)arow * N_FEAT + (tid & 3) * 8;
    unsigned short* a_dst = As + tid * 8;   // byte offset tid*16 == row*64 + kp*16

    // B staging via global_load_lds: chunk c = i*256+tid -> j=c>>2, kp=c&3
    const unsigned short* bg = Wb + (size_t)(tid >> 2) * N_FEAT + (tid & 3) * 8;

    // fragment read pointers
    const unsigned short* ap = As + (lane & 15) * BK + (lane >> 4) * 8;
    const unsigned short* bp = Bs + ((size_t)(wave * 64 + (lane & 15))) * BK + (lane >> 4) * 8;

    f32x4 acc[4][4] = {};

    for (int k0 = 0; k0 < N_FEAT; k0 += BK) {
        if (k0) __syncthreads();   // previous compute done, safe to overwrite
        #pragma unroll
        for (int i = 0; i < 4; i++)
            llds16(bg + (size_t)i * 64 * N_FEAT + k0, Bs + ((size_t)(i * 256 + tid)) * 8);
        const float4 x0 = *(const float4*)(ag + k0);
        const float4 x1 = *(const float4*)(ag + k0 + 4);
        union { unsigned short s[8]; uint4 u; } pk;
        pk.s[0] = bfu(x0.x); pk.s[1] = bfu(x0.y); pk.s[2] = bfu(x0.z); pk.s[3] = bfu(x0.w);
        pk.s[4] = bfu(x1.x); pk.s[5] = bfu(x1.y); pk.s[6] = bfu(x1.z); pk.s[7] = bfu(x1.w);
        *(uint4*)a_dst = pk.u;
        __syncthreads();           // staging (incl. global_load_lds) visible

        bf16x8 af[4], bfr[4];
        #pragma unroll
        for (int mt = 0; mt < 4; mt++) af[mt] = *(const bf16x8*)(ap + mt * 16 * BK);
        #pragma unroll
        for (int nt = 0; nt < 4; nt++) bfr[nt] = *(const bf16x8*)(bp + nt * 16 * BK);
        #pragma unroll
        for (int mt = 0; mt < 4; mt++)
            #pragma unroll
            for (int nt = 0; nt < 4; nt++)
                acc[mt][nt] = __builtin_amdgcn_mfma_f32_16x16x32_bf16(
                    af[mt], bfr[nt], acc[mt][nt], 0, 0, 0);
    }

    // epilogue: C/D layout col=lane&15, row=(lane>>4)*4+reg
    const int q  = lane >> 4;
    const int c0 = lane & 15;
    float bcol[4];
    #pragma unroll
    for (int nt = 0; nt < 4; nt++) bcol[nt] = bias[wave * 64 + nt * 16 + c0];
    #pragma unroll
    for (int mt = 0; mt < 4; mt++) {
        #pragma unroll
        for (int r = 0; r < 4; r++) {
            const int row = m0 + mt * 16 + q * 4 + r;
            if (row >= N) continue;
            #pragma unroll
            for (int nt = 0; nt < 4; nt++) {
                const int col = wave * 64 + nt * 16 + c0;
                Hout[(size_t)row * N_HID + col] = bfu(acc[mt][nt][r] + bcol[nt]);
            }
        }
    }
}

// ---------------- CSR build ------------------------------------------------
// Pass 1: ONE returning atomic per edge computes counts AND per-edge rank.
// bucket = row*4 + (e&3): 4-way replication -> 4x less same-address contention.
__global__ __launch_bounds__(256) void rank_pass(
    const int* __restrict__ rows, int* __restrict__ counts2,
    int* __restrict__ rank, int E)
{
    const int e = blockIdx.x * 256 + threadIdx.x;
    if (e >= E) return;
    const int b = rows[e] * KREP + (e & (KREP - 1));
    rank[e] = atomicAdd(&counts2[b], 1);
}

// ---- parallel exclusive scan over NB2 bucket counts (3 dispatches) --------
// Conservative: shared-memory tree reduce / Hillis-Steele, full barriers.

// Pass A: per-block sums of SCC counts.
__global__ __launch_bounds__(256) void scan_sum(
    const int* __restrict__ counts, int* __restrict__ bsum, int n)
{
    __shared__ int sh[256];
    const int g = blockIdx.x, t = threadIdx.x;
    const int base = g * SCC;
    int s = 0;
    #pragma unroll
    for (int i = 0; i < 4; i++) {
        const int idx = base + t + i * 256;
        if (idx < n) s += counts[idx];
    }
    sh[t] = s;
    __syncthreads();
    for (int off = 128; off > 0; off >>= 1) {
        if (t < off) sh[t] += sh[t + off];
        __syncthreads();
    }
    if (t == 0) bsum[g] = sh[0];
}

// Pass B: single-block exclusive scan of the G block sums (G <= 512).
__global__ __launch_bounds__(512) void scan_base(
    const int* __restrict__ bsum, int* __restrict__ bbase, int G)
{
    __shared__ int sh[512];
    const int t = threadIdx.x;
    const int v = (t < G) ? bsum[t] : 0;
    sh[t] = v;
    __syncthreads();
    for (int off = 1; off < 512; off <<= 1) {
        const int u = (t >= off) ? sh[t - off] : 0;
        __syncthreads();
        sh[t] += u;
        __syncthreads();
    }
    if (t < G) bbase[t] = sh[t] - v;   // exclusive prefix
}

// Pass C: per-block exclusive scan of SCC counts + block base -> offs2.
__global__ __launch_bounds__(256) void scan_write(
    const int* __restrict__ counts, const int* __restrict__ bbase,
    int* __restrict__ offs2, int n, int E)
{
    __shared__ int sh[256];
    const int g = blockIdx.x, t = threadIdx.x;
    const int base = g * SCC;
    int c[4];
    int s = 0;
    #pragma unroll
    for (int i = 0; i < 4; i++) {
        const int idx = base + t * 4 + i;
        c[i] = (idx < n) ? counts[idx] : 0;
        s += c[i];
    }
    sh[t] = s;
    __syncthreads();
    for (int off = 1; off < 256; off <<= 1) {
        const int u = (t >= off) ? sh[t - off] : 0;
        __syncthreads();
        sh[t] += u;
        __syncthreads();
    }
    int run = bbase[g] + sh[t] - s;    // exclusive prefix of this thread's chunk
    #pragma unroll
    for (int i = 0; i < 4; i++) {
        const int idx = base + t * 4 + i;
        if (idx < n) offs2[idx] = run;
        run += c[i];
    }
    if (g == 0 && t == 0) offs2[n] = E;
}

// Pass 2: atomic-free scatter. pos = offs2[bucket] + rank[e].
__global__ __launch_bounds__(256) void scatter_edges(
    const int* __restrict__ rows, const int* __restrict__ cols,
    const float* __restrict__ ev, const int* __restrict__ rank,
    const int* __restrict__ offs2, int2* __restrict__ ecv, int E)
{
    const int e = blockIdx.x * 256 + threadIdx.x;
    if (e >= E) return;
    const int b = rows[e] * KREP + (e & (KREP - 1));
    const int pos = offs2[b] + rank[e];
    int2 p;
    p.x = cols[e];
    p.y = __float_as_int(ev[e]);
    ecv[pos] = p;
}

// ---------------- per-row aggregation --------------------------------------
__device__ __forceinline__ void bf4_unpack(uint2 raw, float& f0, float& f1,
                                           float& f2, float& f3)
{
    f0 = __uint_as_float(raw.x << 16);
    f1 = __uint_as_float(raw.x & 0xffff0000u);
    f2 = __uint_as_float(raw.y << 16);
    f3 = __uint_as_float(raw.y & 0xffff0000u);
}

__device__ __forceinline__ uint2 bf4_pack(float f0, float f1, float f2, float f3)
{
    union { unsigned short u[4]; uint2 v; } pk;
    pk.u[0] = bfu(f0); pk.u[1] = bfu(f1); pk.u[2] = bfu(f2); pk.u[3] = bfu(f3);
    return pk.v;
}

// GCN1: aggregate -> PReLU -> store h_post bf16
// 8-deep unroll: keep 8 gathers in flight per wave (MLP), all reg indices static.
__global__ __launch_bounds__(256) void agg_rows_1(
    const __hip_bfloat16* __restrict__ H, const int* __restrict__ offs2,
    const int2* __restrict__ ecv, const float* __restrict__ pa,
    __hip_bfloat16* __restrict__ hpost, int N)
{
    const int row = blockIdx.x * 4 + (threadIdx.x >> 6);
    if (row >= N) return;
    const int lane = threadIdx.x & 63;
    const int beg = offs2[row * KREP], end = offs2[row * KREP + KREP];
    const unsigned short* Hs = (const unsigned short*)H;

    float a0 = 0.f, a1 = 0.f, a2 = 0.f, a3 = 0.f;
    int e = beg;
    for (; e + 7 < end; e += 8) {
        int2 p[8];
        #pragma unroll
        for (int i = 0; i < 8; i++) p[i] = ecv[e + i];
        uint2 r[8];
        #pragma unroll
        for (int i = 0; i < 8; i++)
            r[i] = *(const uint2*)(Hs + (size_t)p[i].x * N_HID + lane * 4);
        #pragma unroll
        for (int i = 0; i < 8; i++) {
            const float v = __int_as_float(p[i].y);
            float f0, f1, f2, f3;
            bf4_unpack(r[i], f0, f1, f2, f3);
            a0 += v * f0; a1 += v * f1; a2 += v * f2; a3 += v * f3;
        }
    }
    for (; e + 3 < end; e += 4) {
        int2 p[4];
        #pragma unroll
        for (int i = 0; i < 4; i++) p[i] = ecv[e + i];
        uint2 r[4];
        #pragma unroll
        for (int i = 0; i < 4; i++)
            r[i] = *(const uint2*)(Hs + (size_t)p[i].x * N_HID + lane * 4);
        #pragma unroll
        for (int i = 0; i < 4; i++) {
            const float v = __int_as_float(p[i].y);
            float f0, f1, f2, f3;
            bf4_unpack(r[i], f0, f1, f2, f3);
            a0 += v * f0; a1 += v * f1; a2 += v * f2; a3 += v * f3;
        }
    }
    for (; e < end; e++) {
        const int2 p0 = ecv[e];
        const float v0 = __int_as_float(p0.y);
        const uint2 r0 = *(const uint2*)(Hs + (size_t)p0.x * N_HID + lane * 4);
        float f0, f1, f2, f3;
        bf4_unpack(r0, f0, f1, f2, f3);
        a0 += v0 * f0; a1 += v0 * f1; a2 += v0 * f2; a3 += v0 * f3;
    }
    const float al = pa[0];
    a0 = (a0 >= 0.f) ? a0 : al * a0;
    a1 = (a1 >= 0.f) ? a1 : al * a1;
    a2 = (a2 >= 0.f) ? a2 : al * a2;
    a3 = (a3 >= 0.f) ? a3 : al * a3;
    *(uint2*)((unsigned short*)hpost + (size_t)row * N_HID + lane * 4) =
        bf4_pack(a0, a1, a2, a3);
}

// GCN2: aggregate -> PReLU -> dot(v) -> score (same 8-deep unroll)
__global__ __launch_bounds__(256) void agg_rows_2(
    const __hip_bfloat16* __restrict__ H, const int* __restrict__ offs2,
    const int2* __restrict__ ecv, const float* __restrict__ pa,
    const float* __restrict__ vbuf, const float* __restrict__ bilb,
    float* __restrict__ out, int N)
{
    __shared__ float vs[N_HID];
    vs[threadIdx.x] = vbuf[threadIdx.x];
    __syncthreads();

    const int row = blockIdx.x * 4 + (threadIdx.x >> 6);
    if (row >= N) return;
    const int lane = threadIdx.x & 63;
    const int beg = offs2[row * KREP], end = offs2[row * KREP + KREP];
    const unsigned short* Hs = (const unsigned short*)H;

    float a0 = 0.f, a1 = 0.f, a2 = 0.f, a3 = 0.f;
    int e = beg;
    for (; e + 7 < end; e += 8) {
        int2 p[8];
        #pragma unroll
        for (int i = 0; i < 8; i++) p[i] = ecv[e + i];
        uint2 r[8];
        #pragma unroll
        for (int i = 0; i < 8; i++)
            r[i] = *(const uint2*)(Hs + (size_t)p[i].x * N_HID + lane * 4);
        #pragma unroll
        for (int i = 0; i < 8; i++) {
            const float v = __int_as_float(p[i].y);
            float f0, f1, f2, f3;
            bf4_unpack(r[i], f0, f1, f2, f3);
            a0 += v * f0; a1 += v * f1; a2 += v * f2; a3 += v * f3;
        }
    }
    for (; e + 3 < end; e += 4) {
        int2 p[4];
        #pragma unroll
        for (int i = 0; i < 4; i++) p[i] = ecv[e + i];
        uint2 r[4];
        #pragma unroll
        for (int i = 0; i < 4; i++)
            r[i] = *(const uint2*)(Hs + (size_t)p[i].x * N_HID + lane * 4);
        #pragma unroll
        for (int i = 0; i < 4; i++) {
            const float v = __int_as_float(p[i].y);
            float f0, f1, f2, f3;
            bf4_unpack(r[i], f0, f1, f2, f3);
            a0 += v * f0; a1 += v * f1; a2 += v * f2; a3 += v * f3;
        }
    }
    for (; e < end; e++) {
        const int2 p0 = ecv[e];
        const float v0 = __int_as_float(p0.y);
        const uint2 r0 = *(const uint2*)(Hs + (size_t)p0.x * N_HID + lane * 4);
        float f0, f1, f2, f3;
        bf4_unpack(r0, f0, f1, f2, f3);
        a0 += v0 * f0; a1 += v0 * f1; a2 += v0 * f2; a3 += v0 * f3;
    }
    const float al = pa[0];
    a0 = (a0 >= 0.f) ? a0 : al * a0;
    a1 = (a1 >= 0.f) ? a1 : al * a1;
    a2 = (a2 >= 0.f) ? a2 : al * a2;
    a3 = (a3 >= 0.f) ? a3 : al * a3;

    float p = a0 * vs[lane * 4 + 0] + a1 * vs[lane * 4 + 1] +
              a2 * vs[lane * 4 + 2] + a3 * vs[lane * 4 + 3];
    #pragma unroll
    for (int off = 32; off > 0; off >>= 1) p += __shfl_down(p, off);
    if (lane == 0) out[row] = p + bilb[0];
}

// ---------------- column sums of bf16 h_post -------------------------------
#define NPB 256
__global__ __launch_bounds__(256) void colsum_kernel(
    const __hip_bfloat16* __restrict__ hpost, float* __restrict__ colsum, int N)
{
    const int j = threadIdx.x;
    const int n0 = blockIdx.x * NPB;
    const int n1 = min(n0 + NPB, N);
    float s = 0.f;
    for (int n = n0; n < n1; n++)
        s += __bfloat162float(hpost[(size_t)n * N_HID + j]);
    atomicAdd(&colsum[j], s);
}

// ---------------- v = bil_w @ sigmoid(colsum/N) ----------------------------
__global__ __launch_bounds__(256) void compute_v(
    const float* __restrict__ colsum, const float* __restrict__ bilw,
    float* __restrict__ vbuf, int N)
{
    __shared__ float s[N_HID];
    const int t = threadIdx.x;
    const float mean = colsum[t] / (float)N;
    s[t] = 1.f / (1.f + expf(-mean));
    __syncthreads();
    float acc = 0.f;
    #pragma unroll 4
    for (int g = 0; g < N_HID; g++) acc += bilw[t * N_HID + g] * s[g];
    vbuf[t] = acc;
}

// ---------------- score_1: dot(h_post bf16, v) -----------------------------
__global__ __launch_bounds__(256) void score_kernel(
    const __hip_bfloat16* __restrict__ hpost, const float* __restrict__ vbuf,
    const float* __restrict__ bilb, float* __restrict__ out, int N)
{
    __shared__ float vs[N_HID];
    vs[threadIdx.x] = vbuf[threadIdx.x];
    __syncthreads();
    const int n = blockIdx.x * 4 + (threadIdx.x >> 6);
    if (n >= N) return;
    const int lane = threadIdx.x & 63;
    const uint2 raw = *(const uint2*)((const unsigned short*)hpost +
                                      (size_t)n * N_HID + lane * 4);
    float f0, f1, f2, f3;
    bf4_unpack(raw, f0, f1, f2, f3);
    float p = f0 * vs[lane * 4 + 0] + f1 * vs[lane * 4 + 1] +
              f2 * vs[lane * 4 + 2] + f3 * vs[lane * 4 + 3];
    #pragma unroll
    for (int off = 32; off > 0; off >>= 1) p += __shfl_down(p, off);
    if (lane == 0) out[n] = p + bilb[0];
}

extern "C" void kernel_launch(void* const* d_in, const int* in_sizes, int n_in,
                              void* d_out, int out_size, void* d_ws, size_t ws_size,
                              hipStream_t stream)
{
    const float* x1     = (const float*)d_in[0];
    const float* x2     = (const float*)d_in[1];
    const float* evals  = (const float*)d_in[2];
    const float* fc_w   = (const float*)d_in[3];
    const float* fc_b   = (const float*)d_in[4];
    const float* prelua = (const float*)d_in[5];
    const float* bil_w  = (const float*)d_in[6];
    const float* bil_b  = (const float*)d_in[7];
    const int*   eidx   = (const int*)d_in[8];
    const int*   erow   = eidx;
    const int*   ecol   = eidx + N_EDGES;
    float* out = (float*)d_out;

    // workspace layout (bytes) — persistent:
    char* ws = (char*)d_ws;
    __hip_bfloat16* h_bf   = (__hip_bfloat16*)(ws);                         // 51.2 MB
    __hip_bfloat16* hpost1 = (__hip_bfloat16*)(ws + (size_t)52 * 1000000);  // 51.2 MB
    int2*  ecv    = (int2*) (ws + (size_t)104 * 1000000);                   // 25.6 MB
    unsigned short* wbf = (unsigned short*)(ws + (size_t)130 * 1000000);    // 262 KB
    int*   offs2  = (int*)  (ws + (size_t)130400000);                       // 1.6 MB (NB2+1)
    float* colsum = (float*)(ws + (size_t)132100000);                       // 1 KB
    float* vbuf   = colsum + N_HID;
    // transients (inside h_bf region; all dead before gemm_mfma writes h_bf):
    int*   counts2 = (int*)(ws);                                            // 1.6 MB
    int*   bsum    = (int*)(ws + (size_t)2000000);                          // 1.6 KB
    int*   bbase   = (int*)(ws + (size_t)2010000);                          // 1.6 KB
    int*   rank    = (int*)(ws + (size_t)4000000);                          // 12.8 MB

    const int gemm_blocks = (N_NODES + BM - 1) / BM;
    const int eblocks   = (N_EDGES + 255) / 256;
    const int rowblocks = (N_NODES + 3) / 4;
    const int csblocks  = (N_NODES + NPB - 1) / NPB;

    // ---- CSR build (single atomic pass, parallel scan) + W convert ----
    hipMemsetAsync(counts2, 0, NB2 * sizeof(int), stream);
    hipMemsetAsync(colsum, 0, N_HID * sizeof(float), stream);
    rank_pass<<<eblocks, 256, 0, stream>>>(erow, counts2, rank, N_EDGES);
    scan_sum<<<SCG, 256, 0, stream>>>(counts2, bsum, NB2);
    scan_base<<<1, 512, 0, stream>>>(bsum, bbase, SCG);
    scan_write<<<SCG, 256, 0, stream>>>(counts2, bbase, offs2, NB2, N_EDGES);
    scatter_edges<<<eblocks, 256, 0, stream>>>(erow, ecol, evals, rank,
                                               offs2, ecv, N_EDGES);
    convert_bf16_kernel<<<(N_HID * N_FEAT / 8 + 255) / 256, 256, 0, stream>>>(
        fc_w, wbf, N_HID * N_FEAT / 8);

    // ---- GCN 1 ----
    gemm_mfma<<<gemm_blocks, 256, 0, stream>>>(x1, wbf, fc_b,
                                               (unsigned short*)h_bf, N_NODES);
    agg_rows_1<<<rowblocks, 256, 0, stream>>>(h_bf, offs2, ecv, prelua,
                                              hpost1, N_NODES);
    colsum_kernel<<<csblocks, 256, 0, stream>>>(hpost1, colsum, N_NODES);
    compute_v<<<1, 256, 0, stream>>>(colsum, bil_w, vbuf, N_NODES);
    score_kernel<<<rowblocks, 256, 0, stream>>>(hpost1, vbuf, bil_b, out, N_NODES);

    // ---- GCN 2 (reuses h_bf, CSR; fused score) ----
    gemm_mfma<<<gemm_blocks, 256, 0, stream>>>(x2, wbf, fc_b,
                                               (unsigned short*)h_bf, N_NODES);
    agg_rows_2<<<rowblocks, 256, 0, stream>>>(h_bf, offs2, ecv, prelua,
                                              vbuf, bil_b, out + N_NODES, N_NODES);
}